// Round 16
// baseline (98.819 us; speedup 1.0000x reference)
//
#include <hip/hip_runtime.h>
#include <math.h>

#define NQ 16
#define NBATCH 512
#define NCLS 100

typedef float v2f __attribute__((ext_vector_type(2)));
typedef __fp16 f16x2 __attribute__((ext_vector_type(2)));
typedef _Float16 half8 __attribute__((ext_vector_type(8)));
typedef float f32x4 __attribute__((ext_vector_type(4)));

__device__ __forceinline__ v2f mkv(float x, float y){ v2f r; r.x = x; r.y = y; return r; }
__device__ __forceinline__ f16x2 pack_h(v2f a){ return __builtin_amdgcn_cvt_pkrtz(a.x, a.y); }
__device__ __forceinline__ f16x2 pack_h2(float a, float b){ return __builtin_amdgcn_cvt_pkrtz(a, b); }
__device__ __forceinline__ v2f unpack_h(f16x2 h){ return mkv((float)h.x, (float)h.y); }

// fp8 (OCP e4m3) pack/unpack via ISA (low 16 bits carry 2 fp8 values)
__device__ __forceinline__ unsigned pack_fp8(float a, float b){
  unsigned u;
  asm("v_cvt_pk_fp8_f32 %0, %1, %2" : "=v"(u) : "v"(a), "v"(b));
  return u;
}
__device__ __forceinline__ v2f unpack_fp8(unsigned u){
  v2f f;
  asm("v_cvt_pk_f32_fp8 %0, %1" : "=v"(f) : "v"(u));
  return f;
}

union pack16 { f16x2 h[4]; uint4 u; };

// ---- packed-f32 complex primitives (VOP3P v_pk_*) ----
__device__ __forceinline__ v2f pk_cmul(v2f a, v2f b){
  v2f t, d;
  asm("v_pk_mul_f32 %0, %1, %2 op_sel:[0,0] op_sel_hi:[1,0]"
      : "=v"(t) : "v"(a), "v"(b));
  asm("v_pk_fma_f32 %0, %1, %2, %3 op_sel:[1,1,0] op_sel_hi:[0,1,1] neg_lo:[1,0,0]"
      : "=v"(d) : "v"(a), "v"(b), "v"(t));
  return d;
}
__device__ __forceinline__ v2f pk_cmul_acc(v2f a, v2f b, v2f acc){
  v2f t, d;
  asm("v_pk_fma_f32 %0, %1, %2, %3 op_sel:[0,0,0] op_sel_hi:[1,0,1]"
      : "=v"(t) : "v"(a), "v"(b), "v"(acc));
  asm("v_pk_fma_f32 %0, %1, %2, %3 op_sel:[1,1,0] op_sel_hi:[0,1,1] neg_lo:[1,0,0]"
      : "=v"(d) : "v"(a), "v"(b), "v"(t));
  return d;
}
// plain elementwise packed fma: d = a*b + c
__device__ __forceinline__ v2f pk_fma_el(v2f a, v2f b, v2f c){
  v2f d;
  asm("v_pk_fma_f32 %0, %1, %2, %3"
      : "=v"(d) : "v"(a), "v"(b), "v"(c));
  return d;
}
// RX pair rotation with cs=(c,s)
__device__ __forceinline__ void pk_rx(v2f &a, v2f &b, v2f cs){
  v2f t1, t2, na, nb;
  asm("v_pk_mul_f32 %0, %1, %2 op_sel:[0,0] op_sel_hi:[0,1]"
      : "=v"(t1) : "v"(cs), "v"(a));
  asm("v_pk_mul_f32 %0, %1, %2 op_sel:[0,0] op_sel_hi:[0,1]"
      : "=v"(t2) : "v"(cs), "v"(b));
  asm("v_pk_fma_f32 %0, %1, %2, %3 op_sel:[1,1,0] op_sel_hi:[1,0,1] neg_hi:[0,1,0]"
      : "=v"(na) : "v"(cs), "v"(b), "v"(t1));
  asm("v_pk_fma_f32 %0, %1, %2, %3 op_sel:[1,1,0] op_sel_hi:[1,0,1] neg_hi:[0,1,0]"
      : "=v"(nb) : "v"(cs), "v"(a), "v"(t2));
  a = na; b = nb;
}

// CRX with per-lane predicate ctrl
template<int MT>
__device__ __forceinline__ void crx_pred(v2f (&v)[16], bool on, v2f cs){
  v2f id = mkv(1.f, 0.f);
  v2f cs_p = on ? cs : id;
  #pragma unroll
  for (int r=0;r<16;r++) if(!(r&MT)) pk_rx(v[r], v[r|MT], cs_p);
}
// CRX applied unconditionally
template<int MT>
__device__ __forceinline__ void crx_on(v2f (&v)[16], v2f cs){
  #pragma unroll
  for (int r=0;r<16;r++) if(!(r&MT)) pk_rx(v[r], v[r|MT], cs);
}
// CRX ctrl and tgt both register bits
template<int MC,int MT>
__device__ __forceinline__ void crx_rr(v2f (&v)[16], v2f cs){
  #pragma unroll
  for (int r=0;r<16;r++) if((r&MC)&&!(r&MT)) pk_rx(v[r], v[r|MT], cs);
}
// full 1q gate on register bit M
template<int M>
__device__ __forceinline__ void reg_gate(v2f (&v)[16], v2f u00, v2f u01, v2f u10, v2f u11){
  #pragma unroll
  for (int r=0;r<16;r++) if(!(r&M)){
    v2f a = v[r], b = v[r|M];
    v[r]   = pk_cmul_acc(u01, b, pk_cmul(u00, a));
    v[r|M] = pk_cmul_acc(u11, b, pk_cmul(u10, a));
  }
}
// F = RX(cs) . W
__device__ __forceinline__ void build_rxw(v2f cs, v2f w00, v2f w01, v2f w10, v2f w11,
      v2f &f00, v2f &f01, v2f &f10, v2f &f11){
  f00 = w00; f10 = w10; pk_rx(f00, f10, cs);
  f01 = w01; f11 = w11; pk_rx(f01, f11, cs);
}

__device__ __forceinline__ int lds_phys(int c){ return c ^ (((c>>4)^(c>>8))&15); }
// 16B-chunk swizzled address (uint4 units), canonical layout [m(8b)][kb(4b)]
__device__ __forceinline__ int swz(int m, int q){
  return m*4 + (q ^ (m&3) ^ ((m>>2)&3));
}
// 4B swizzle for the pass2 output re-layout buffer
__device__ __forceinline__ int oswz(int idx){ return idx ^ ((idx>>5)&31); }

// Precompute fused U_i^b = Rot_i * RX(x[b,i]) (both layers) + CRX (c,s) pairs
// Also zeroes expv (replaces the hipMemsetAsync dispatch).
__global__ __launch_bounds__(256) void kprep(const float* __restrict__ x,
      const float* __restrict__ rot1, const float* __restrict__ crx1,
      const float* __restrict__ rot2, const float* __restrict__ crx2,
      v2f* __restrict__ fU, v2f* __restrict__ cm, float* __restrict__ expv)
{
  int t = blockIdx.x*blockDim.x + threadIdx.x;
  if (t < NBATCH*NQ) expv[t] = 0.f;
  if (t < 2*NBATCH*NQ){
    int w  = t & 15;
    int bb = (t>>4) & (NBATCH-1);
    int L  = t >> 13;
    const float* rot = L ? rot2 : rot1;
    float phi = rot[w*3+0], th = rot[w*3+1], om = rot[w*3+2];
    float ct = cosf(0.5f*th), stt = sinf(0.5f*th);
    float a1 = 0.5f*(phi+om), a2 = 0.5f*(phi-om);
    float emx = cosf(a1), emy = -sinf(a1);
    float epx = cosf(a1), epy =  sinf(a1);
    float edmx = cosf(a2), edmy = -sinf(a2);
    float edpx = cosf(a2), edpy =  sinf(a2);
    float R00x = emx*ct,   R00y = emy*ct;
    float R01x = -edpx*stt, R01y = -edpy*stt;
    float R10x = edmx*stt, R10y = edmy*stt;
    float R11x = epx*ct,   R11y = epy*ct;
    float xv = x[bb*NQ + w];
    float cx = cosf(0.5f*xv), sx = sinf(0.5f*xv);
    v2f* o = fU + (size_t)t*4;
    o[0] = mkv(R00x*cx + R01y*sx,  R00y*cx - R01x*sx);
    o[1] = mkv(R00y*sx + R01x*cx, -R00x*sx + R01y*cx);
    o[2] = mkv(R10x*cx + R11y*sx,  R10y*cx - R11x*sx);
    o[3] = mkv(R10y*sx + R11x*cx, -R10x*sx + R11y*cx);
  }
  if (t < 2*NQ){
    int L = t>>4, w = t&15;
    const float* cxl = L ? crx2 : crx1;
    float thc = cxl[w];
    cm[t] = mkv(cosf(0.5f*thc), sinf(0.5f*thc));
  }
}

// Shared B-fragment store: B1[2r][n]=Re G[n][r], B1[2r+1][n]=-Im; B2: Im, Re.
__device__ __forceinline__ void store_Bfrag(_Float16* Bt16, size_t hb, int r0, const v2f (&v)[16]){
  int k0 = 2*r0;
  int lk = 16*(k0>>3);
  int j0 = k0 & 7;
  #pragma unroll
  for (int n=0;n<16;n++){
    _Float16 re  = (_Float16)v[n].x;
    _Float16 im  = (_Float16)v[n].y;
    _Float16 nim = (_Float16)(-v[n].y);
    size_t ln = (size_t)(lk + n);
    Bt16[((hb+0)*64 + ln)*8 + j0]   = re;
    Bt16[((hb+0)*64 + ln)*8 + j0+1] = nim;
    Bt16[((hb+1)*64 + ln)*8 + j0]   = im;
    Bt16[((hb+1)*64 + ln)*8 + j0+1] = re;
  }
}

// merged prep: B tables for pass3 (Bt16), pass2 (Bt16b), and L1-tail table Tbl
__global__ __launch_bounds__(256) void kprepGall(const v2f* __restrict__ fU1,
      const v2f* __restrict__ fU2,
      const v2f* __restrict__ cm1, const v2f* __restrict__ cm2,
      _Float16* __restrict__ Bt16, _Float16* __restrict__ Bt16b,
      v2f* __restrict__ Tbl)
{
  int tt = blockIdx.x*blockDim.x + threadIdx.x;
  if (tt >= 2*32768 + 2*NBATCH) return;
  if (tt >= 2*32768){
    // L1-tail table
    int t = tt - 2*32768;
    int bb = t >> 1, bit = t & 1;
    const v2f* U = fU1 + (size_t)bb*64;
    v2f p[16];
    p[0] = U[48]; p[1] = U[50];
    p[2] = pk_cmul(p[0], U[54]); p[3] = pk_cmul(p[1], U[54]);
    p[0] = pk_cmul(p[0], U[52]); p[1] = pk_cmul(p[1], U[52]);
    #pragma unroll
    for (int i=0;i<4;i++){ p[i+4]=pk_cmul(p[i],U[58]); p[i]=pk_cmul(p[i],U[56]); }
    #pragma unroll
    for (int i=0;i<8;i++){ p[i+8]=pk_cmul(p[i],U[62]); p[i]=pk_cmul(p[i],U[60]); }
    if (bit){
      #pragma unroll
      for (int r=0;r<16;r++) if(!(r&1)) pk_rx(p[r], p[r|1], cm1[11]);
    }
    #pragma unroll
    for (int r=0;r<16;r++) if((r&1)&&!(r&2)) pk_rx(p[r], p[r|2], cm1[12]);
    #pragma unroll
    for (int r=0;r<16;r++) if((r&2)&&!(r&4)) pk_rx(p[r], p[r|4], cm1[13]);
    #pragma unroll
    for (int r=0;r<16;r++) if((r&4)&&!(r&8)) pk_rx(p[r], p[r|8], cm1[14]);
    v2f* o = Tbl + ((size_t)bb<<5) + (bit<<4);
    #pragma unroll
    for (int r=0;r<16;r++) o[r] = p[r];
    return;
  }
  int which = tt >> 15;            // 0: pass3 table, 1: pass2 table
  int t = tt & 32767;
  int r0 = t & 15;
  int var = (t>>4) & 1;
  int stage = (t>>5) & 1;
  int bg = t >> 6;
  const v2f* U2 = fU2 + ((size_t)bg<<6);
  v2f v[16];
  #pragma unroll
  for (int r=0;r<16;r++) v[r] = mkv(0.f,0.f);
  v[r0] = mkv(1.f,0.f);
  if (which == 0){
    if (stage == 0){
      reg_gate<1>(v, U2[28],U2[29],U2[30],U2[31]);   // W7
      reg_gate<2>(v, U2[32],U2[33],U2[34],U2[35]);   // W8
      reg_gate<4>(v, U2[36],U2[37],U2[38],U2[39]);   // W9
      reg_gate<8>(v, U2[40],U2[41],U2[42],U2[43]);   // W10
      if (var) crx_on<1>(v, cm2[6]);                 // CRX(6,7)
      crx_rr<1,2>(v, cm2[7]);
      crx_rr<2,4>(v, cm2[8]);
      crx_rr<4,8>(v, cm2[9]);
    } else {
      reg_gate<1>(v, U2[44],U2[45],U2[46],U2[47]);   // W11
      reg_gate<2>(v, U2[48],U2[49],U2[50],U2[51]);   // W12
      reg_gate<4>(v, U2[52],U2[53],U2[54],U2[55]);   // W13
      reg_gate<8>(v, U2[56],U2[57],U2[58],U2[59]);   // W14
      if (var) crx_on<1>(v, cm2[10]);                // CRX(10,11)
      crx_rr<1,2>(v, cm2[11]);
      crx_rr<2,4>(v, cm2[12]);
      crx_rr<4,8>(v, cm2[13]);
    }
    size_t hb = (((size_t)bg*2 + stage)*2 + var)*2;
    store_Bfrag(Bt16, hb, r0, v);
  } else {
    if (stage == 0){
      if (var) crx_on<1>(v, cm1[15]);                // L1 CRX(15,0) on w0
      reg_gate<1>(v, U2[0], U2[1], U2[2], U2[3]);    // W0
      reg_gate<2>(v, U2[4], U2[5], U2[6], U2[7]);    // W1
      reg_gate<4>(v, U2[8], U2[9], U2[10],U2[11]);   // W2
      reg_gate<8>(v, U2[12],U2[13],U2[14],U2[15]);   // W3
      crx_rr<1,2>(v, cm2[0]);                        // CRX(0,1)
      crx_rr<2,4>(v, cm2[1]);                        // CRX(1,2)
      crx_rr<4,8>(v, cm2[2]);                        // CRX(2,3)
    } else {
      reg_gate<1>(v, U2[16],U2[17],U2[18],U2[19]);   // W4
      reg_gate<2>(v, U2[20],U2[21],U2[22],U2[23]);   // W5
      reg_gate<4>(v, U2[24],U2[25],U2[26],U2[27]);   // W6
      if (var) crx_on<1>(v, cm2[3]);                 // CRX(3,4) on w4
      crx_rr<1,2>(v, cm2[4]);                        // CRX(4,5)
      crx_rr<2,4>(v, cm2[5]);                        // CRX(5,6)
    }
    size_t hb = (((size_t)bg*2 + stage)*2 + var)*2;
    store_Bfrag(Bt16b, hb, r0, v);
  }
}

// ---------------------------------------------------------------------------
// PASS 1: unchanged
__global__ __launch_bounds__(256) void kpass1(const v2f* __restrict__ fU1,
      const v2f* __restrict__ cm1, f16x2* __restrict__ compact)
{
  int lane = threadIdx.x & 63;
  int wv = threadIdx.x >> 6;
  int bg = blockIdx.x;
  const v2f* U = fU1 + ((size_t)bg<<6);
  v2f a = (lane&1) ? U[2] : U[0];
  a = pk_cmul(a, ((lane>>1)&1) ? U[22] : U[20]);
  a = pk_cmul(a, ((lane>>2)&1) ? U[26] : U[24]);
  a = pk_cmul(a, ((lane>>3)&1) ? U[30] : U[28]);
  a = pk_cmul(a, ((lane>>4)&1) ? U[34] : U[32]);
  a = pk_cmul(a, ((lane>>5)&1) ? U[38] : U[36]);
  a = pk_cmul(a, (wv&1) ? U[42] : U[40]);
  a = pk_cmul(a, ((wv>>1)&1) ? U[46] : U[44]);
  v2f v[16];
  v[0] = pk_cmul(a, U[4]);    v[1] = pk_cmul(a, U[6]);
  v[2] = pk_cmul(v[0], U[10]); v[3] = pk_cmul(v[1], U[10]);
  v[0] = pk_cmul(v[0], U[8]);  v[1] = pk_cmul(v[1], U[8]);
  #pragma unroll
  for (int i=0;i<4;i++){ v[i+4]=pk_cmul(v[i],U[14]); v[i]=pk_cmul(v[i],U[12]); }
  #pragma unroll
  for (int i=0;i<8;i++){ v[i+8]=pk_cmul(v[i],U[18]); v[i]=pk_cmul(v[i],U[16]); }
  crx_pred<1>(v, (lane&1)!=0, cm1[0]);
  crx_rr<1,2>(v, cm1[1]);
  crx_rr<2,4>(v, cm1[2]);
  crx_rr<4,8>(v, cm1[3]);
  __shared__ v2f lds[4096];
  #pragma unroll
  for (int r=0;r<16;r++){
    int c = (lane&1) | (r<<1) | (((lane>>1)&31)<<5) | (wv<<10);
    lds[lds_phys(c)] = v[r];
  }
  __syncthreads();
  #pragma unroll
  for (int r=0;r<16;r++){
    int c = ((lane>>1)&15) | ((lane&1)<<4) | (r<<5) | (((lane>>5)&1)<<9) | (wv<<10);
    v[r] = lds[lds_phys(c)];
  }
  crx_pred<1>(v, (lane&1)!=0, cm1[4]);
  crx_rr<1,2>(v, cm1[5]);
  crx_rr<2,4>(v, cm1[6]);
  crx_rr<4,8>(v, cm1[7]);
  __syncthreads();
  #pragma unroll
  for (int r=0;r<16;r++){
    int c = ((lane>>1)&15) | ((lane&1)<<4) | (r<<5) | (((lane>>5)&1)<<9) | (wv<<10);
    lds[lds_phys(c)] = v[r];
  }
  __syncthreads();
  #pragma unroll
  for (int r=0;r<16;r++){
    int c = (lane&63) | (wv<<6) | (((r>>3)&1)<<8) | ((r&7)<<9);
    v[r] = lds[lds_phys(c)];
  }
  crx_rr<8,1>(v, cm1[8]);
  crx_rr<1,2>(v, cm1[9]);
  crx_rr<2,4>(v, cm1[10]);
  __syncthreads();
  #pragma unroll
  for (int r=0;r<16;r++){
    int c = (lane&63) | (wv<<6) | (((r>>3)&1)<<8) | ((r&7)<<9);
    lds[lds_phys(c)] = v[r];
  }
  __syncthreads();
  f16x2* outp = compact + ((size_t)bg<<12);
  #pragma unroll
  for (int r=0;r<16;r++){
    int c = ((lane>>1)&31) | (wv<<5) | (r<<7) | ((lane&1)<<11);
    outp[lane | (wv<<6) | (r<<8)] = pack_h(lds[lds_phys(c)]);
  }
}

// ---------------------------------------------------------------------------
// PASS 2 (MFMA): 2 h-groups per block, XCD-aware block decode.
__global__ __launch_bounds__(256) void kpass2(const f16x2* __restrict__ compact,
      const v2f* __restrict__ Tbl, const half8* __restrict__ Btab2,
      unsigned short* __restrict__ st, int b0)
{
  int lane = threadIdx.x & 63;
  int wv = threadIdx.x >> 6;
  int g = blockIdx.x;
  int cx = g & 7, q = g >> 3;
  int h8 = q & 7;
  int bl = cx + 8*(q>>3);
  int bg = b0 + bl;
  __shared__ uint4 lbuf[1024];
  f16x2* lbufH = (f16x2*)lbuf;

  const v2f* T = Tbl + ((size_t)bg<<5) + ((lane&1)<<4);   // w11 = lane bit 0
  int sel = wv & 1;
  size_t hb1 = (((size_t)bg*2 + 0)*2 + sel)*2;
  size_t hb2 = (((size_t)bg*2 + 1)*2 + sel)*2;
  half8 B1a = Btab2[(hb1+0)*64 + lane];
  half8 B2a = Btab2[(hb1+1)*64 + lane];
  half8 B1b = Btab2[(hb2+0)*64 + lane];
  half8 B2b = Btab2[(hb2+1)*64 + lane];
  f32x4 zz = {0.f, 0.f, 0.f, 0.f};
  int kb = (lane>>1) & 15;                 // w0..w3
  int mA_fix = (lane&1) | ((lane>>5)<<4) | ((wv&1)<<5) | ((wv>>1)<<7);
  int n = lane & 15, lq = lane >> 4;
  int q_c = ((wv>>1)&1) | ((n&1)<<1);      // (w6, w0)
  unsigned short* S = st + ((size_t)bl<<16);

  for (int hh=0; hh<2; hh++){
    int h = h8 + 8*hh;
    if (hh) __syncthreads();
    v2f a = unpack_h(compact[((size_t)bg<<12) | (size_t)(lane | (wv<<6) | (h<<8))]);
    // stage A: v[r'] = a * T[r'], scatter to canonical1 (f16)
    #pragma unroll
    for (int r=0;r<16;r++){
      v2f val = pk_cmul(a, T[r]);
      int m = mA_fix | ((r&7)<<1) | ((r>>3)<<6);
      lbufH[swz(m, kb>>2)*4 + (kb&3)] = pack_h(val);
    }
    __syncthreads();
    uint4 af1[4];
    #pragma unroll
    for (int t=0;t<4;t++){
      int m = (wv<<6) | (t<<4) | (lane&15);
      af1[t] = lbuf[swz(m, lane>>4)];
    }
    __syncthreads();
    // stage B
    f32x4 dre[4], dim[4];
    #pragma unroll
    for (int t=0;t<4;t++){
      half8 af = *(const half8*)&af1[t];
      dre[t] = __builtin_amdgcn_mfma_f32_16x16x32_f16(af, B1a, zz, 0, 0, 0);
      dim[t] = __builtin_amdgcn_mfma_f32_16x16x32_f16(af, B2a, zz, 0, 0, 0);
    }
    #pragma unroll
    for (int reg=0;reg<4;reg++){
      int mC = (lq&1) | (((n>>1)&1)<<1) | (((n>>2)&1)<<2) | ((lq>>1)<<3)
             | ((reg&1)<<4) | (((reg>>1)&1)<<5) | (((n>>3)&1)<<6) | ((wv&1)<<7);
      pack16 pk;
      #pragma unroll
      for (int t=0;t<4;t++) pk.h[t] = pack_h2(dre[t][reg], dim[t][reg]);
      lbuf[swz(mC, q_c)] = pk.u;
    }
    __syncthreads();
    uint4 af2[4];
    #pragma unroll
    for (int t2=0;t2<4;t2++){
      int m = (wv<<6) | (t2<<4) | (lane&15);
      af2[t2] = lbuf[swz(m, lane>>4)];
    }
    __syncthreads();
    // stage C: scatter into buffer (R9-st-order index, XOR-swizzled)
    #pragma unroll
    for (int t2=0;t2<4;t2++){
      half8 af = *(const half8*)&af2[t2];
      f32x4 ere = __builtin_amdgcn_mfma_f32_16x16x32_f16(af, B1b, zz, 0, 0, 0);
      f32x4 eim = __builtin_amdgcn_mfma_f32_16x16x32_f16(af, B2b, zz, 0, 0, 0);
      #pragma unroll
      for (int reg=0;reg<4;reg++){
        int idx = ((lane>>3)&1) | (((reg>>1)&1)<<1) | ((t2&1)<<2) | (((t2>>1)&1)<<3)
                | ((reg&1)<<4) | ((wv&1)<<5) | (((lane>>4)&1)<<6) | (((lane>>5)&1)<<7)
                | ((lane&1)<<8) | (((lane>>1)&1)<<9) | (((lane>>2)&1)<<10) | (((wv>>1)&1)<<11);
        lbufH[oswz(idx)] = pack_h2(ere[reg], eim[reg]);
      }
    }
    __syncthreads();
    // linear read + coalesced fp8 st store (R9 layout)
    #pragma unroll
    for (int r=0;r<16;r++){
      int idx = lane | (wv<<6) | (r<<8);
      f16x2 hv = lbufH[oswz(idx)];
      unsigned p8 = pack_fp8((float)hv.x, (float)hv.y);
      S[idx | (h<<12)] = (unsigned short)p8;
    }
  }
}

// ---------------------------------------------------------------------------
// PASS 3 (MFMA): 2 h-groups per block (h8, h8+8), merged epilogue.
__global__ __launch_bounds__(256) void kpass3(const unsigned short* __restrict__ st,
      const v2f* __restrict__ fU2, const v2f* __restrict__ cm2,
      const half8* __restrict__ Btab,
      float* __restrict__ expv, int b0)
{
  int lane = threadIdx.x & 63;
  int wv = threadIdx.x >> 6;
  int g = blockIdx.x;
  int cx = g & 7, q = g >> 3;
  int h8 = q & 7;
  int bl = cx + 8*(q>>3);
  int bg = b0 + bl;
  const unsigned short* S = st + ((size_t)bl<<16);
  const v2f* U2 = fU2 + ((size_t)bg<<6);
  __shared__ uint4 lbuf[1024];

  int sel = wv & 1;
  size_t hb1 = (((size_t)bg*2 + 0)*2 + sel)*2;
  size_t hb2 = (((size_t)bg*2 + 1)*2 + sel)*2;
  half8 B1a = Btab[(hb1+0)*64 + lane];
  half8 B2a = Btab[(hb1+1)*64 + lane];
  half8 B1b = Btab[(hb2+0)*64 + lane];
  half8 B2b = Btab[(hb2+1)*64 + lane];
  f32x4 zz = {0.f, 0.f, 0.f, 0.f};
  v2f G00, G01, G10, G11;
  {
    v2f g00=U2[60], g01=U2[61], g10=U2[62], g11=U2[63];
    v2f f00,f01,f10,f11;
    build_rxw(cm2[14], g00,g01,g10,g11, f00,f01,f10,f11);
    bool on3 = ((lane>>3)&1) != 0;   // w14 = col bit 3
    G00 = on3?f00:g00; G01 = on3?f01:g01; G10 = on3?f10:g10; G11 = on3?f11:g11;
  }
  int m1 = ((lane>>2)&15) | (((wv>>1)&1)<<4) | ((lane&1)<<5)
         | ((wv&1)<<6) | (((lane>>1)&1)<<7);

  v2f accT0 = mkv(0.f,0.f), accT1 = mkv(0.f,0.f);
  v2f acc15 = mkv(0.f,0.f), acc0 = mkv(0.f,0.f);
  v2f acc9 = mkv(0.f,0.f), acc1 = mkv(0.f,0.f);

  for (int hh=0; hh<2; hh++){
    int h = h8 + 8*hh;
    if (hh) __syncthreads();
    int abase = (((h>>1)&1)<<5) | ((h&1)<<6) | (((h>>2)&1)<<8) | (((h>>3)&1)<<9)
              | ((wv&1)<<10) | (((wv>>1)&1)<<11);
    f16x2 v[16];
    #pragma unroll
    for (int r=0;r<16;r++){
      unsigned short u8 = S[(lane&31) | (((lane>>5)&1)<<7) | abase | (r<<12)];
      v2f fr = unpack_fp8((unsigned)u8);
      v[r] = pack_h(fr);
    }
    #pragma unroll
    for (int qd=0;qd<4;qd++){
      pack16 pk;
      pk.h[0]=v[4*qd]; pk.h[1]=v[4*qd+1]; pk.h[2]=v[4*qd+2]; pk.h[3]=v[4*qd+3];
      lbuf[swz(m1,qd)] = pk.u;
    }
    __syncthreads();
    uint4 af1[4];
    #pragma unroll
    for (int t=0;t<4;t++){
      int m = (wv<<6) | (t<<4) | (lane&15);
      af1[t] = lbuf[swz(m, lane>>4)];
    }
    __syncthreads();
    // stage 1
    {
      int n = lane & 15;
      int q2 = lane >> 4;
      #pragma unroll
      for (int t=0;t<4;t++){
        half8 af = *(const half8*)&af1[t];
        f32x4 dre = __builtin_amdgcn_mfma_f32_16x16x32_f16(af, B1a, zz, 0, 0, 0);
        f32x4 dim = __builtin_amdgcn_mfma_f32_16x16x32_f16(af, B2a, zz, 0, 0, 0);
        int m2 = t | ((n&7)<<2) | (((wv>>1)&1)<<5) | (((n>>3)&1)<<6) | ((wv&1)<<7);
        pack16 pk;
        #pragma unroll
        for (int rg=0;rg<4;rg++) pk.h[rg] = pack_h2(dre[rg], dim[rg]);
        lbuf[swz(m2, q2)] = pk.u;
      }
    }
    __syncthreads();
    uint4 af2[4];
    #pragma unroll
    for (int t2=0;t2<4;t2++){
      int m = (wv<<6) | (t2<<4) | (lane&15);
      af2[t2] = lbuf[swz(m, lane>>4)];
    }
    // stage 2 + tail
    v2f lT = mkv(0.f,0.f);
    #pragma unroll
    for (int t2=0;t2<4;t2++){
      half8 af = *(const half8*)&af2[t2];
      f32x4 ere = __builtin_amdgcn_mfma_f32_16x16x32_f16(af, B1b, zz, 0, 0, 0);
      f32x4 eim = __builtin_amdgcn_mfma_f32_16x16x32_f16(af, B2b, zz, 0, 0, 0);
      v2f a0 = mkv(ere[0], eim[0]);
      v2f a1 = mkv(ere[1], eim[1]);
      v2f a2 = mkv(ere[2], eim[2]);
      v2f a3 = mkv(ere[3], eim[3]);
      v2f n0 = pk_cmul_acc(G01, a1, pk_cmul(G00, a0));
      v2f n1 = pk_cmul_acc(G11, a1, pk_cmul(G10, a0));
      v2f n2 = pk_cmul_acc(G01, a3, pk_cmul(G00, a2));
      v2f n3 = pk_cmul_acc(G11, a3, pk_cmul(G10, a2));
      pk_rx(n1, n3, cm2[15]);
      v2f q0 = pk_fma_el(n0,n0,mkv(0,0));
      v2f q1 = pk_fma_el(n1,n1,mkv(0,0));
      v2f q2v = pk_fma_el(n2,n2,mkv(0,0));
      v2f q3 = pk_fma_el(n3,n3,mkv(0,0));
      v2f qs = q0+q1+q2v+q3;
      lT += qs;
      acc15 += q1+q3;
      acc0  += q2v+q3;
      if (t2&1) acc9 += qs;
      if (t2&2) acc1 += qs;
    }
    accT0 = (hh==0) ? (accT0+lT) : accT0;
    accT1 = (hh==1) ? (accT1+lT) : accT1;
  }

  float tot0 = accT0.x + accT0.y;
  float tot1 = accT1.x + accT1.y;
  float s  = tot0 + tot1;
  float dd = tot0 - tot1;           // w5 entry: +s(h) for hh=0, -s for hh=1
  float S15 = acc15.x + acc15.y;
  float S0w = acc0.x + acc0.y;
  float S9  = acc9.x + acc9.y;
  float S1w = acc1.x + acc1.y;
  float u[6];
  #pragma unroll
  for (int b=0;b<6;b++){
    int m = 1<<b;
    float tt = __shfl_xor(s, m, 64);
    u[b] = s - tt;
    s = s + tt;
    #pragma unroll
    for (int j=0;j<6;j++) if (j<b) u[j] += __shfl_xor(u[j], m, 64);
  }
  #pragma unroll
  for (int d1=1; d1<64; d1<<=1){
    dd  += __shfl_xor(dd, d1, 64);
    S15 += __shfl_xor(S15, d1, 64);
    S0w += __shfl_xor(S0w, d1, 64);
    S9  += __shfl_xor(S9, d1, 64);
    S1w += __shfl_xor(S1w, d1, 64);
  }
  __syncthreads();
  float* ef = (float*)lbuf;
  if (lane==0){
    ef[wv*16+11]=u[0]; ef[wv*16+12]=u[1]; ef[wv*16+13]=u[2]; ef[wv*16+14]=u[3];
    ef[wv*16+7]=u[4];  ef[wv*16+8]=u[5];
    ef[wv*16+15]=s-2.f*S15; ef[wv*16+0]=s-2.f*S0w;
    ef[wv*16+9]=s-2.f*S9;   ef[wv*16+1]=s-2.f*S1w;
    ef[wv*16+10]=(wv&1)?-s:s; ef[wv*16+6]=(wv&2)?-s:s;
    ef[wv*16+2]=(h8&1)?-s:s; ef[wv*16+3]=(h8&2)?-s:s;
    ef[wv*16+4]=(h8&4)?-s:s; ef[wv*16+5]=dd;
  }
  __syncthreads();
  if (threadIdx.x < 16){
    float r4 = ef[threadIdx.x]+ef[16+threadIdx.x]+ef[32+threadIdx.x]+ef[48+threadIdx.x];
    atomicAdd(expv + (size_t)bg*NQ + threadIdx.x, r4);
  }
}

// klogits: shared-memory tree reductions
__global__ __launch_bounds__(128) void klogits(const float* __restrict__ expv,
      const float* __restrict__ W, const float* __restrict__ bias,
      float* __restrict__ out)
{
  int b = blockIdx.x;
  int tid = threadIdx.x;
  __shared__ float f[NQ];
  __shared__ float lg[128];
  __shared__ float red[128];
  if (tid < NQ) f[tid] = expv[b*NQ + tid];
  __syncthreads();
  float acc = -1e30f;
  if (tid < NCLS){
    acc = bias[tid];
    #pragma unroll
    for (int i=0;i<NQ;i++) acc += f[i]*W[tid*NQ+i];
  }
  lg[tid] = acc;
  red[tid] = acc;
  __syncthreads();
  #pragma unroll
  for (int sft=64; sft>0; sft>>=1){
    if (tid < sft) red[tid] = fmaxf(red[tid], red[tid+sft]);
    __syncthreads();
  }
  float m = red[0];
  __syncthreads();
  float e = (tid < NCLS) ? expf(lg[tid]-m) : 0.f;
  red[tid] = e;
  __syncthreads();
  #pragma unroll
  for (int sft=64; sft>0; sft>>=1){
    if (tid < sft) red[tid] = red[tid] + red[tid+sft];
    __syncthreads();
  }
  float lsum = logf(red[0]);
  if (tid < NCLS) out[b*NCLS+tid] = lg[tid] - m - lsum;
}

extern "C" void kernel_launch(void* const* d_in, const int* in_sizes, int n_in,
                              void* d_out, int out_size, void* d_ws, size_t ws_size,
                              hipStream_t stream)
{
  const float* x    = (const float*)d_in[0];
  const float* rot1 = (const float*)d_in[1];
  const float* crx1 = (const float*)d_in[2];
  const float* rot2 = (const float*)d_in[3];
  const float* crx2 = (const float*)d_in[4];
  const float* W    = (const float*)d_in[5];
  const float* bias = (const float*)d_in[6];
  float* out = (float*)d_out;

  char* ws = (char*)d_ws;
  float* expv = (float*)ws;                           // 32 KB  @ 0
  v2f*   fU   = (v2f*)(ws + (40<<10));                // 512 KB @ 40K
  v2f*   cmm  = (v2f*)(ws + (560<<10));               // 256 B  @ 560K
  v2f*   Tbl  = (v2f*)(ws + (564<<10));               // 128 KB @ 564K
  _Float16* Bt16  = (_Float16*)(ws + (704<<10));      // 4 MB   @ 704K   (pass3)
  _Float16* Bt16b = (_Float16*)(ws + (4800<<10));     // 4 MB   @ 4800K  (pass2)
  f16x2* compact = (f16x2*)(ws + (8896<<10));         // 8 MB   @ 8896K
  const size_t stOff = (size_t)(8896<<10) + ((size_t)NBATCH<<14);   // 17088K
  unsigned short* st = (unsigned short*)(ws + stOff); // 64 MB (fp8 pairs)

  kprep<<<(2*NBATCH*NQ + 255)/256, 256, 0, stream>>>(x, rot1, crx1, rot2, crx2, fU, cmm, expv);

  v2f* fU1 = fU;
  v2f* fU2 = fU + 32768;
  v2f* cm1 = cmm;
  v2f* cm2 = cmm + 16;

  kprepGall<<<(2*32768 + 2*NBATCH + 255)/256, 256, 0, stream>>>(fU1, fU2, cm1, cm2, Bt16, Bt16b, Tbl);
  kpass1<<<NBATCH, 256, 0, stream>>>(fU1, cm1, compact);

  size_t avail = (ws_size > stOff) ? (ws_size - stOff) : 0;
  int chunk = NBATCH;
  while (chunk > 8 && (size_t)chunk*65536*sizeof(unsigned short) > avail) chunk >>= 1;

  for (int b0 = 0; b0 < NBATCH; b0 += chunk){
    kpass2<<<chunk*8, 256, 0, stream>>>(compact, Tbl, (const half8*)Bt16b, st, b0);
    kpass3<<<chunk*8, 256, 0, stream>>>(st, fU2, cm2, (const half8*)Bt16, expv, b0);
  }
  klogits<<<NBATCH, 128, 0, stream>>>(expv, W, bias, out);
}

// Round 17
// 97.356 us; speedup vs baseline: 1.0150x; 1.0150x over previous
//
#include <hip/hip_runtime.h>
#include <math.h>

#define NQ 16
#define NBATCH 512
#define NCLS 100

typedef float v2f __attribute__((ext_vector_type(2)));
typedef __fp16 f16x2 __attribute__((ext_vector_type(2)));
typedef _Float16 half8 __attribute__((ext_vector_type(8)));
typedef float f32x4 __attribute__((ext_vector_type(4)));

__device__ __forceinline__ v2f mkv(float x, float y){ v2f r; r.x = x; r.y = y; return r; }
__device__ __forceinline__ f16x2 pack_h(v2f a){ return __builtin_amdgcn_cvt_pkrtz(a.x, a.y); }
__device__ __forceinline__ f16x2 pack_h2(float a, float b){ return __builtin_amdgcn_cvt_pkrtz(a, b); }
__device__ __forceinline__ v2f unpack_h(f16x2 h){ return mkv((float)h.x, (float)h.y); }

// fp8 (OCP e4m3) pack/unpack via ISA (low 16 bits carry 2 fp8 values)
__device__ __forceinline__ unsigned pack_fp8(float a, float b){
  unsigned u;
  asm("v_cvt_pk_fp8_f32 %0, %1, %2" : "=v"(u) : "v"(a), "v"(b));
  return u;
}
__device__ __forceinline__ v2f unpack_fp8(unsigned u){
  v2f f;
  asm("v_cvt_pk_f32_fp8 %0, %1" : "=v"(f) : "v"(u));
  return f;
}

union pack16 { f16x2 h[4]; uint4 u; };

// ---- packed-f32 complex primitives (VOP3P v_pk_*) ----
__device__ __forceinline__ v2f pk_cmul(v2f a, v2f b){
  v2f t, d;
  asm("v_pk_mul_f32 %0, %1, %2 op_sel:[0,0] op_sel_hi:[1,0]"
      : "=v"(t) : "v"(a), "v"(b));
  asm("v_pk_fma_f32 %0, %1, %2, %3 op_sel:[1,1,0] op_sel_hi:[0,1,1] neg_lo:[1,0,0]"
      : "=v"(d) : "v"(a), "v"(b), "v"(t));
  return d;
}
__device__ __forceinline__ v2f pk_cmul_acc(v2f a, v2f b, v2f acc){
  v2f t, d;
  asm("v_pk_fma_f32 %0, %1, %2, %3 op_sel:[0,0,0] op_sel_hi:[1,0,1]"
      : "=v"(t) : "v"(a), "v"(b), "v"(acc));
  asm("v_pk_fma_f32 %0, %1, %2, %3 op_sel:[1,1,0] op_sel_hi:[0,1,1] neg_lo:[1,0,0]"
      : "=v"(d) : "v"(a), "v"(b), "v"(t));
  return d;
}
// plain elementwise packed fma: d = a*b + c
__device__ __forceinline__ v2f pk_fma_el(v2f a, v2f b, v2f c){
  v2f d;
  asm("v_pk_fma_f32 %0, %1, %2, %3"
      : "=v"(d) : "v"(a), "v"(b), "v"(c));
  return d;
}
// RX pair rotation with cs=(c,s)
__device__ __forceinline__ void pk_rx(v2f &a, v2f &b, v2f cs){
  v2f t1, t2, na, nb;
  asm("v_pk_mul_f32 %0, %1, %2 op_sel:[0,0] op_sel_hi:[0,1]"
      : "=v"(t1) : "v"(cs), "v"(a));
  asm("v_pk_mul_f32 %0, %1, %2 op_sel:[0,0] op_sel_hi:[0,1]"
      : "=v"(t2) : "v"(cs), "v"(b));
  asm("v_pk_fma_f32 %0, %1, %2, %3 op_sel:[1,1,0] op_sel_hi:[1,0,1] neg_hi:[0,1,0]"
      : "=v"(na) : "v"(cs), "v"(b), "v"(t1));
  asm("v_pk_fma_f32 %0, %1, %2, %3 op_sel:[1,1,0] op_sel_hi:[1,0,1] neg_hi:[0,1,0]"
      : "=v"(nb) : "v"(cs), "v"(a), "v"(t2));
  a = na; b = nb;
}

// CRX with per-lane predicate ctrl
template<int MT>
__device__ __forceinline__ void crx_pred(v2f (&v)[16], bool on, v2f cs){
  v2f id = mkv(1.f, 0.f);
  v2f cs_p = on ? cs : id;
  #pragma unroll
  for (int r=0;r<16;r++) if(!(r&MT)) pk_rx(v[r], v[r|MT], cs_p);
}
// CRX applied unconditionally
template<int MT>
__device__ __forceinline__ void crx_on(v2f (&v)[16], v2f cs){
  #pragma unroll
  for (int r=0;r<16;r++) if(!(r&MT)) pk_rx(v[r], v[r|MT], cs);
}
// CRX ctrl and tgt both register bits
template<int MC,int MT>
__device__ __forceinline__ void crx_rr(v2f (&v)[16], v2f cs){
  #pragma unroll
  for (int r=0;r<16;r++) if((r&MC)&&!(r&MT)) pk_rx(v[r], v[r|MT], cs);
}
// full 1q gate on register bit M
template<int M>
__device__ __forceinline__ void reg_gate(v2f (&v)[16], v2f u00, v2f u01, v2f u10, v2f u11){
  #pragma unroll
  for (int r=0;r<16;r++) if(!(r&M)){
    v2f a = v[r], b = v[r|M];
    v[r]   = pk_cmul_acc(u01, b, pk_cmul(u00, a));
    v[r|M] = pk_cmul_acc(u11, b, pk_cmul(u10, a));
  }
}
// F = RX(cs) . W
__device__ __forceinline__ void build_rxw(v2f cs, v2f w00, v2f w01, v2f w10, v2f w11,
      v2f &f00, v2f &f01, v2f &f10, v2f &f11){
  f00 = w00; f10 = w10; pk_rx(f00, f10, cs);
  f01 = w01; f11 = w11; pk_rx(f01, f11, cs);
}

__device__ __forceinline__ int lds_phys(int c){ return c ^ (((c>>4)^(c>>8))&15); }
// 16B-chunk swizzled address (uint4 units), canonical layout [m(8b)][kb(4b)]
__device__ __forceinline__ int swz(int m, int q){
  return m*4 + (q ^ (m&3) ^ ((m>>2)&3));
}
// 4B swizzle for the pass2 output re-layout buffer
__device__ __forceinline__ int oswz(int idx){ return idx ^ ((idx>>5)&31); }

// Precompute fused U_i^b = Rot_i * RX(x[b,i]) (both layers) + CRX (c,s) pairs
// Also zeroes expv (replaces the hipMemsetAsync dispatch).
__global__ __launch_bounds__(256) void kprep(const float* __restrict__ x,
      const float* __restrict__ rot1, const float* __restrict__ crx1,
      const float* __restrict__ rot2, const float* __restrict__ crx2,
      v2f* __restrict__ fU, v2f* __restrict__ cm, float* __restrict__ expv)
{
  int t = blockIdx.x*blockDim.x + threadIdx.x;
  if (t < NBATCH*NQ) expv[t] = 0.f;
  if (t < 2*NBATCH*NQ){
    int w  = t & 15;
    int bb = (t>>4) & (NBATCH-1);
    int L  = t >> 13;
    const float* rot = L ? rot2 : rot1;
    float phi = rot[w*3+0], th = rot[w*3+1], om = rot[w*3+2];
    float ct = cosf(0.5f*th), stt = sinf(0.5f*th);
    float a1 = 0.5f*(phi+om), a2 = 0.5f*(phi-om);
    float emx = cosf(a1), emy = -sinf(a1);
    float epx = cosf(a1), epy =  sinf(a1);
    float edmx = cosf(a2), edmy = -sinf(a2);
    float edpx = cosf(a2), edpy =  sinf(a2);
    float R00x = emx*ct,   R00y = emy*ct;
    float R01x = -edpx*stt, R01y = -edpy*stt;
    float R10x = edmx*stt, R10y = edmy*stt;
    float R11x = epx*ct,   R11y = epy*ct;
    float xv = x[bb*NQ + w];
    float cx = cosf(0.5f*xv), sx = sinf(0.5f*xv);
    v2f* o = fU + (size_t)t*4;
    o[0] = mkv(R00x*cx + R01y*sx,  R00y*cx - R01x*sx);
    o[1] = mkv(R00y*sx + R01x*cx, -R00x*sx + R01y*cx);
    o[2] = mkv(R10x*cx + R11y*sx,  R10y*cx - R11x*sx);
    o[3] = mkv(R10y*sx + R11x*cx, -R10x*sx + R11y*cx);
  }
  if (t < 2*NQ){
    int L = t>>4, w = t&15;
    const float* cxl = L ? crx2 : crx1;
    float thc = cxl[w];
    cm[t] = mkv(cosf(0.5f*thc), sinf(0.5f*thc));
  }
}

// Shared B-fragment store: B1[2r][n]=Re G[n][r], B1[2r+1][n]=-Im; B2: Im, Re.
__device__ __forceinline__ void store_Bfrag(_Float16* Bt16, size_t hb, int r0, const v2f (&v)[16]){
  int k0 = 2*r0;
  int lk = 16*(k0>>3);
  int j0 = k0 & 7;
  #pragma unroll
  for (int n=0;n<16;n++){
    _Float16 re  = (_Float16)v[n].x;
    _Float16 im  = (_Float16)v[n].y;
    _Float16 nim = (_Float16)(-v[n].y);
    size_t ln = (size_t)(lk + n);
    Bt16[((hb+0)*64 + ln)*8 + j0]   = re;
    Bt16[((hb+0)*64 + ln)*8 + j0+1] = nim;
    Bt16[((hb+1)*64 + ln)*8 + j0]   = im;
    Bt16[((hb+1)*64 + ln)*8 + j0+1] = re;
  }
}

// merged prep: B tables for pass3 (Bt16), pass2 (Bt16b), and L1-tail table Tbl
__global__ __launch_bounds__(256) void kprepGall(const v2f* __restrict__ fU1,
      const v2f* __restrict__ fU2,
      const v2f* __restrict__ cm1, const v2f* __restrict__ cm2,
      _Float16* __restrict__ Bt16, _Float16* __restrict__ Bt16b,
      v2f* __restrict__ Tbl)
{
  int tt = blockIdx.x*blockDim.x + threadIdx.x;
  if (tt >= 2*32768 + 2*NBATCH) return;
  if (tt >= 2*32768){
    // L1-tail table
    int t = tt - 2*32768;
    int bb = t >> 1, bit = t & 1;
    const v2f* U = fU1 + (size_t)bb*64;
    v2f p[16];
    p[0] = U[48]; p[1] = U[50];
    p[2] = pk_cmul(p[0], U[54]); p[3] = pk_cmul(p[1], U[54]);
    p[0] = pk_cmul(p[0], U[52]); p[1] = pk_cmul(p[1], U[52]);
    #pragma unroll
    for (int i=0;i<4;i++){ p[i+4]=pk_cmul(p[i],U[58]); p[i]=pk_cmul(p[i],U[56]); }
    #pragma unroll
    for (int i=0;i<8;i++){ p[i+8]=pk_cmul(p[i],U[62]); p[i]=pk_cmul(p[i],U[60]); }
    if (bit){
      #pragma unroll
      for (int r=0;r<16;r++) if(!(r&1)) pk_rx(p[r], p[r|1], cm1[11]);
    }
    #pragma unroll
    for (int r=0;r<16;r++) if((r&1)&&!(r&2)) pk_rx(p[r], p[r|2], cm1[12]);
    #pragma unroll
    for (int r=0;r<16;r++) if((r&2)&&!(r&4)) pk_rx(p[r], p[r|4], cm1[13]);
    #pragma unroll
    for (int r=0;r<16;r++) if((r&4)&&!(r&8)) pk_rx(p[r], p[r|8], cm1[14]);
    v2f* o = Tbl + ((size_t)bb<<5) + (bit<<4);
    #pragma unroll
    for (int r=0;r<16;r++) o[r] = p[r];
    return;
  }
  int which = tt >> 15;            // 0: pass3 table, 1: pass2 table
  int t = tt & 32767;
  int r0 = t & 15;
  int var = (t>>4) & 1;
  int stage = (t>>5) & 1;
  int bg = t >> 6;
  const v2f* U2 = fU2 + ((size_t)bg<<6);
  v2f v[16];
  #pragma unroll
  for (int r=0;r<16;r++) v[r] = mkv(0.f,0.f);
  v[r0] = mkv(1.f,0.f);
  if (which == 0){
    if (stage == 0){
      reg_gate<1>(v, U2[28],U2[29],U2[30],U2[31]);   // W7
      reg_gate<2>(v, U2[32],U2[33],U2[34],U2[35]);   // W8
      reg_gate<4>(v, U2[36],U2[37],U2[38],U2[39]);   // W9
      reg_gate<8>(v, U2[40],U2[41],U2[42],U2[43]);   // W10
      if (var) crx_on<1>(v, cm2[6]);                 // CRX(6,7)
      crx_rr<1,2>(v, cm2[7]);
      crx_rr<2,4>(v, cm2[8]);
      crx_rr<4,8>(v, cm2[9]);
    } else {
      reg_gate<1>(v, U2[44],U2[45],U2[46],U2[47]);   // W11
      reg_gate<2>(v, U2[48],U2[49],U2[50],U2[51]);   // W12
      reg_gate<4>(v, U2[52],U2[53],U2[54],U2[55]);   // W13
      reg_gate<8>(v, U2[56],U2[57],U2[58],U2[59]);   // W14
      if (var) crx_on<1>(v, cm2[10]);                // CRX(10,11)
      crx_rr<1,2>(v, cm2[11]);
      crx_rr<2,4>(v, cm2[12]);
      crx_rr<4,8>(v, cm2[13]);
    }
    size_t hb = (((size_t)bg*2 + stage)*2 + var)*2;
    store_Bfrag(Bt16, hb, r0, v);
  } else {
    if (stage == 0){
      if (var) crx_on<1>(v, cm1[15]);                // L1 CRX(15,0) on w0
      reg_gate<1>(v, U2[0], U2[1], U2[2], U2[3]);    // W0
      reg_gate<2>(v, U2[4], U2[5], U2[6], U2[7]);    // W1
      reg_gate<4>(v, U2[8], U2[9], U2[10],U2[11]);   // W2
      reg_gate<8>(v, U2[12],U2[13],U2[14],U2[15]);   // W3
      crx_rr<1,2>(v, cm2[0]);                        // CRX(0,1)
      crx_rr<2,4>(v, cm2[1]);                        // CRX(1,2)
      crx_rr<4,8>(v, cm2[2]);                        // CRX(2,3)
    } else {
      reg_gate<1>(v, U2[16],U2[17],U2[18],U2[19]);   // W4
      reg_gate<2>(v, U2[20],U2[21],U2[22],U2[23]);   // W5
      reg_gate<4>(v, U2[24],U2[25],U2[26],U2[27]);   // W6
      if (var) crx_on<1>(v, cm2[3]);                 // CRX(3,4) on w4
      crx_rr<1,2>(v, cm2[4]);                        // CRX(4,5)
      crx_rr<2,4>(v, cm2[5]);                        // CRX(5,6)
    }
    size_t hb = (((size_t)bg*2 + stage)*2 + var)*2;
    store_Bfrag(Bt16b, hb, r0, v);
  }
}

// ---------------------------------------------------------------------------
// PASS 1: unchanged
__global__ __launch_bounds__(256) void kpass1(const v2f* __restrict__ fU1,
      const v2f* __restrict__ cm1, f16x2* __restrict__ compact)
{
  int lane = threadIdx.x & 63;
  int wv = threadIdx.x >> 6;
  int bg = blockIdx.x;
  const v2f* U = fU1 + ((size_t)bg<<6);
  v2f a = (lane&1) ? U[2] : U[0];
  a = pk_cmul(a, ((lane>>1)&1) ? U[22] : U[20]);
  a = pk_cmul(a, ((lane>>2)&1) ? U[26] : U[24]);
  a = pk_cmul(a, ((lane>>3)&1) ? U[30] : U[28]);
  a = pk_cmul(a, ((lane>>4)&1) ? U[34] : U[32]);
  a = pk_cmul(a, ((lane>>5)&1) ? U[38] : U[36]);
  a = pk_cmul(a, (wv&1) ? U[42] : U[40]);
  a = pk_cmul(a, ((wv>>1)&1) ? U[46] : U[44]);
  v2f v[16];
  v[0] = pk_cmul(a, U[4]);    v[1] = pk_cmul(a, U[6]);
  v[2] = pk_cmul(v[0], U[10]); v[3] = pk_cmul(v[1], U[10]);
  v[0] = pk_cmul(v[0], U[8]);  v[1] = pk_cmul(v[1], U[8]);
  #pragma unroll
  for (int i=0;i<4;i++){ v[i+4]=pk_cmul(v[i],U[14]); v[i]=pk_cmul(v[i],U[12]); }
  #pragma unroll
  for (int i=0;i<8;i++){ v[i+8]=pk_cmul(v[i],U[18]); v[i]=pk_cmul(v[i],U[16]); }
  crx_pred<1>(v, (lane&1)!=0, cm1[0]);
  crx_rr<1,2>(v, cm1[1]);
  crx_rr<2,4>(v, cm1[2]);
  crx_rr<4,8>(v, cm1[3]);
  __shared__ v2f lds[4096];
  #pragma unroll
  for (int r=0;r<16;r++){
    int c = (lane&1) | (r<<1) | (((lane>>1)&31)<<5) | (wv<<10);
    lds[lds_phys(c)] = v[r];
  }
  __syncthreads();
  #pragma unroll
  for (int r=0;r<16;r++){
    int c = ((lane>>1)&15) | ((lane&1)<<4) | (r<<5) | (((lane>>5)&1)<<9) | (wv<<10);
    v[r] = lds[lds_phys(c)];
  }
  crx_pred<1>(v, (lane&1)!=0, cm1[4]);
  crx_rr<1,2>(v, cm1[5]);
  crx_rr<2,4>(v, cm1[6]);
  crx_rr<4,8>(v, cm1[7]);
  __syncthreads();
  #pragma unroll
  for (int r=0;r<16;r++){
    int c = ((lane>>1)&15) | ((lane&1)<<4) | (r<<5) | (((lane>>5)&1)<<9) | (wv<<10);
    lds[lds_phys(c)] = v[r];
  }
  __syncthreads();
  #pragma unroll
  for (int r=0;r<16;r++){
    int c = (lane&63) | (wv<<6) | (((r>>3)&1)<<8) | ((r&7)<<9);
    v[r] = lds[lds_phys(c)];
  }
  crx_rr<8,1>(v, cm1[8]);
  crx_rr<1,2>(v, cm1[9]);
  crx_rr<2,4>(v, cm1[10]);
  __syncthreads();
  #pragma unroll
  for (int r=0;r<16;r++){
    int c = (lane&63) | (wv<<6) | (((r>>3)&1)<<8) | ((r&7)<<9);
    lds[lds_phys(c)] = v[r];
  }
  __syncthreads();
  f16x2* outp = compact + ((size_t)bg<<12);
  #pragma unroll
  for (int r=0;r<16;r++){
    int c = ((lane>>1)&31) | (wv<<5) | (r<<7) | ((lane&1)<<11);
    outp[lane | (wv<<6) | (r<<8)] = pack_h(lds[lds_phys(c)]);
  }
}

// ---------------------------------------------------------------------------
// PASS 2 (MFMA, single 16 KB LDS buffer); st stored as fp8 (e4m3) pairs
__global__ __launch_bounds__(256) void kpass2(const f16x2* __restrict__ compact,
      const v2f* __restrict__ Tbl, const half8* __restrict__ Btab2,
      unsigned short* __restrict__ st, int b0)
{
  int lane = threadIdx.x & 63;
  int wv = threadIdx.x >> 6;
  int blk = blockIdx.x;
  int bl = blk >> 4, h = blk & 15;
  int bg = b0 + bl;
  __shared__ uint4 lbuf[1024];
  f16x2* lbufH = (f16x2*)lbuf;

  v2f a = unpack_h(compact[((size_t)bg<<12) | (size_t)(lane | (wv<<6) | (h<<8))]);
  const v2f* T = Tbl + ((size_t)bg<<5) + ((lane&1)<<4);   // w11 = lane bit 0
  int sel = wv & 1;
  size_t hb1 = (((size_t)bg*2 + 0)*2 + sel)*2;
  size_t hb2 = (((size_t)bg*2 + 1)*2 + sel)*2;
  half8 B1a = Btab2[(hb1+0)*64 + lane];
  half8 B2a = Btab2[(hb1+1)*64 + lane];
  f32x4 zz = {0.f, 0.f, 0.f, 0.f};

  // stage A: v[r'] = a * T[r'], scatter to canonical1 (f16)
  int kb = (lane>>1) & 15;                 // w0..w3
  int mA_fix = (lane&1) | ((lane>>5)<<4) | ((wv&1)<<5) | ((wv>>1)<<7);
  #pragma unroll
  for (int r=0;r<16;r++){
    v2f val = pk_cmul(a, T[r]);
    int m = mA_fix | ((r&7)<<1) | ((r>>3)<<6);
    lbufH[swz(m, kb>>2)*4 + (kb&3)] = pack_h(val);
  }
  __syncthreads();
  // pre-read stage-B A-frags
  uint4 af1[4];
  #pragma unroll
  for (int t=0;t<4;t++){
    int m = (wv<<6) | (t<<4) | (lane&15);
    af1[t] = lbuf[swz(m, lane>>4)];
  }
  __syncthreads();

  // stage B: G_B MFMA, write canonical2 into same buffer
  f32x4 dre[4], dim[4];
  #pragma unroll
  for (int t=0;t<4;t++){
    half8 af = *(const half8*)&af1[t];
    dre[t] = __builtin_amdgcn_mfma_f32_16x16x32_f16(af, B1a, zz, 0, 0, 0);
    dim[t] = __builtin_amdgcn_mfma_f32_16x16x32_f16(af, B2a, zz, 0, 0, 0);
  }
  int n = lane & 15, lq = lane >> 4;
  int q_c = ((wv>>1)&1) | ((n&1)<<1);      // (w6, w0)
  #pragma unroll
  for (int reg=0;reg<4;reg++){
    int mC = (lq&1) | (((n>>1)&1)<<1) | (((n>>2)&1)<<2) | ((lq>>1)<<3)
           | ((reg&1)<<4) | (((reg>>1)&1)<<5) | (((n>>3)&1)<<6) | ((wv&1)<<7);
    pack16 pk;
    #pragma unroll
    for (int t=0;t<4;t++) pk.h[t] = pack_h2(dre[t][reg], dim[t][reg]);
    lbuf[swz(mC, q_c)] = pk.u;
  }
  __syncthreads();
  // pre-read stage-C A-frags
  uint4 af2[4];
  #pragma unroll
  for (int t2=0;t2<4;t2++){
    int m = (wv<<6) | (t2<<4) | (lane&15);
    af2[t2] = lbuf[swz(m, lane>>4)];
  }
  __syncthreads();

  // stage C: G_C MFMA, scatter into buffer (R9-st-order index, XOR-swizzled)
  half8 B1b = Btab2[(hb2+0)*64 + lane];
  half8 B2b = Btab2[(hb2+1)*64 + lane];
  #pragma unroll
  for (int t2=0;t2<4;t2++){
    half8 af = *(const half8*)&af2[t2];
    f32x4 ere = __builtin_amdgcn_mfma_f32_16x16x32_f16(af, B1b, zz, 0, 0, 0);
    f32x4 eim = __builtin_amdgcn_mfma_f32_16x16x32_f16(af, B2b, zz, 0, 0, 0);
    #pragma unroll
    for (int reg=0;reg<4;reg++){
      int idx = ((lane>>3)&1) | (((reg>>1)&1)<<1) | ((t2&1)<<2) | (((t2>>1)&1)<<3)
              | ((reg&1)<<4) | ((wv&1)<<5) | (((lane>>4)&1)<<6) | (((lane>>5)&1)<<7)
              | ((lane&1)<<8) | (((lane>>1)&1)<<9) | (((lane>>2)&1)<<10) | (((wv>>1)&1)<<11);
      lbufH[oswz(idx)] = pack_h2(ere[reg], eim[reg]);
    }
  }
  __syncthreads();

  // linear read + coalesced fp8 st store (R9 layout)
  unsigned short* S = st + ((size_t)bl<<16);
  #pragma unroll
  for (int r=0;r<16;r++){
    int idx = lane | (wv<<6) | (r<<8);
    f16x2 hv = lbufH[oswz(idx)];
    unsigned p8 = pack_fp8((float)hv.x, (float)hv.y);
    S[idx | (h<<12)] = (unsigned short)p8;
  }
}

// ---------------------------------------------------------------------------
// PASS 3 (MFMA, single 16 KB LDS buffer); st read as fp8 pairs
__global__ __launch_bounds__(256) void kpass3(const unsigned short* __restrict__ st,
      const v2f* __restrict__ fU2, const v2f* __restrict__ cm2,
      const half8* __restrict__ Btab,
      float* __restrict__ expv, int b0)
{
  int lane = threadIdx.x & 63;
  int wv = threadIdx.x >> 6;
  int blk = blockIdx.x;
  int bl = blk >> 4, h = blk & 15;
  int bg = b0 + bl;
  const unsigned short* S = st + ((size_t)bl<<16);
  const v2f* U2 = fU2 + ((size_t)bg<<6);
  __shared__ uint4 lbuf[1024];

  int abase = (((h>>1)&1)<<5) | ((h&1)<<6) | (((h>>2)&1)<<8) | (((h>>3)&1)<<9)
            | ((wv&1)<<10) | (((wv>>1)&1)<<11);
  f16x2 v[16];
  #pragma unroll
  for (int r=0;r<16;r++){
    unsigned short u8 = S[(lane&31) | (((lane>>5)&1)<<7) | abase | (r<<12)];
    v2f fr = unpack_fp8((unsigned)u8);
    v[r] = pack_h(fr);
  }
  int m1 = ((lane>>2)&15) | (((wv>>1)&1)<<4) | ((lane&1)<<5)
         | ((wv&1)<<6) | (((lane>>1)&1)<<7);
  #pragma unroll
  for (int q=0;q<4;q++){
    pack16 pk;
    pk.h[0]=v[4*q]; pk.h[1]=v[4*q+1]; pk.h[2]=v[4*q+2]; pk.h[3]=v[4*q+3];
    lbuf[swz(m1,q)] = pk.u;
  }
  int sel = wv & 1;
  size_t hb1 = (((size_t)bg*2 + 0)*2 + sel)*2;
  size_t hb2 = (((size_t)bg*2 + 1)*2 + sel)*2;
  half8 B1a = Btab[(hb1+0)*64 + lane];
  half8 B2a = Btab[(hb1+1)*64 + lane];
  f32x4 zz = {0.f, 0.f, 0.f, 0.f};
  __syncthreads();
  // pre-read stage-1 A-frags
  uint4 af1[4];
  #pragma unroll
  for (int t=0;t<4;t++){
    int m = (wv<<6) | (t<<4) | (lane&15);
    af1[t] = lbuf[swz(m, lane>>4)];
  }
  __syncthreads();

  // stage 1: G1 MFMA, write canonical2 into same buffer
  {
    int n = lane & 15;
    int q2 = lane >> 4;
    #pragma unroll
    for (int t=0;t<4;t++){
      half8 af = *(const half8*)&af1[t];
      f32x4 dre = __builtin_amdgcn_mfma_f32_16x16x32_f16(af, B1a, zz, 0, 0, 0);
      f32x4 dim = __builtin_amdgcn_mfma_f32_16x16x32_f16(af, B2a, zz, 0, 0, 0);
      int m2 = t | ((n&7)<<2) | (((wv>>1)&1)<<5) | (((n>>3)&1)<<6) | ((wv&1)<<7);
      pack16 pk;
      #pragma unroll
      for (int rg=0;rg<4;rg++) pk.h[rg] = pack_h2(dre[rg], dim[rg]);
      lbuf[swz(m2, q2)] = pk.u;
    }
  }
  __syncthreads();
  // pre-read stage-2 A-frags
  uint4 af2[4];
  #pragma unroll
  for (int t2=0;t2<4;t2++){
    int m = (wv<<6) | (t2<<4) | (lane&15);
    af2[t2] = lbuf[swz(m, lane>>4)];
  }

  // stage 2: G2 MFMA + VALU tail + expval
  half8 B1b = Btab[(hb2+0)*64 + lane];
  half8 B2b = Btab[(hb2+1)*64 + lane];
  v2f G00, G01, G10, G11;
  {
    v2f g00=U2[60], g01=U2[61], g10=U2[62], g11=U2[63];
    v2f f00,f01,f10,f11;
    build_rxw(cm2[14], g00,g01,g10,g11, f00,f01,f10,f11);
    bool on3 = ((lane>>3)&1) != 0;   // w14 = col bit 3
    G00 = on3?f00:g00; G01 = on3?f01:g01; G10 = on3?f10:g10; G11 = on3?f11:g11;
  }
  v2f accT = mkv(0.f,0.f), acc15 = mkv(0.f,0.f), acc0 = mkv(0.f,0.f);
  v2f acc9 = mkv(0.f,0.f), acc1 = mkv(0.f,0.f);
  #pragma unroll
  for (int t2=0;t2<4;t2++){
    half8 af = *(const half8*)&af2[t2];
    f32x4 ere = __builtin_amdgcn_mfma_f32_16x16x32_f16(af, B1b, zz, 0, 0, 0);
    f32x4 eim = __builtin_amdgcn_mfma_f32_16x16x32_f16(af, B2b, zz, 0, 0, 0);
    v2f a0 = mkv(ere[0], eim[0]);
    v2f a1 = mkv(ere[1], eim[1]);
    v2f a2 = mkv(ere[2], eim[2]);
    v2f a3 = mkv(ere[3], eim[3]);
    v2f n0 = pk_cmul_acc(G01, a1, pk_cmul(G00, a0));
    v2f n1 = pk_cmul_acc(G11, a1, pk_cmul(G10, a0));
    v2f n2 = pk_cmul_acc(G01, a3, pk_cmul(G00, a2));
    v2f n3 = pk_cmul_acc(G11, a3, pk_cmul(G10, a2));
    pk_rx(n1, n3, cm2[15]);
    v2f q0 = pk_fma_el(n0,n0,mkv(0,0));
    v2f q1 = pk_fma_el(n1,n1,mkv(0,0));
    v2f q2v = pk_fma_el(n2,n2,mkv(0,0));
    v2f q3 = pk_fma_el(n3,n3,mkv(0,0));
    v2f qs = q0+q1+q2v+q3;
    accT += qs;
    acc15 += q1+q3;
    acc0  += q2v+q3;
    if (t2&1) acc9 += qs;
    if (t2&2) acc1 += qs;
  }
  float tot = accT.x + accT.y;
  float S15 = acc15.x + acc15.y;
  float S0w = acc0.x + acc0.y;
  float S9  = acc9.x + acc9.y;
  float S1w = acc1.x + acc1.y;
  float s = tot;
  float u[6];
  #pragma unroll
  for (int b=0;b<6;b++){
    int m = 1<<b;
    float tt = __shfl_xor(s, m, 64);
    u[b] = s - tt;
    s = s + tt;
    #pragma unroll
    for (int j=0;j<6;j++) if (j<b) u[j] += __shfl_xor(u[j], m, 64);
  }
  #pragma unroll
  for (int d=1; d<64; d<<=1){
    S15 += __shfl_xor(S15, d, 64);
    S0w += __shfl_xor(S0w, d, 64);
    S9  += __shfl_xor(S9, d, 64);
    S1w += __shfl_xor(S1w, d, 64);
  }
  __syncthreads();
  float* ef = (float*)lbuf;
  if (lane==0){
    ef[wv*16+11]=u[0]; ef[wv*16+12]=u[1]; ef[wv*16+13]=u[2]; ef[wv*16+14]=u[3];
    ef[wv*16+7]=u[4];  ef[wv*16+8]=u[5];
    ef[wv*16+15]=s-2.f*S15; ef[wv*16+0]=s-2.f*S0w;
    ef[wv*16+9]=s-2.f*S9;   ef[wv*16+1]=s-2.f*S1w;
    ef[wv*16+10]=(wv&1)?-s:s; ef[wv*16+6]=(wv&2)?-s:s;
    ef[wv*16+2]=(h&1)?-s:s; ef[wv*16+3]=(h&2)?-s:s;
    ef[wv*16+4]=(h&4)?-s:s; ef[wv*16+5]=(h&8)?-s:s;
  }
  __syncthreads();
  if (threadIdx.x < 16){
    float r4 = ef[threadIdx.x]+ef[16+threadIdx.x]+ef[32+threadIdx.x]+ef[48+threadIdx.x];
    atomicAdd(expv + (size_t)bg*NQ + threadIdx.x, r4);
  }
}

// klogits: shared-memory tree reductions
__global__ __launch_bounds__(128) void klogits(const float* __restrict__ expv,
      const float* __restrict__ W, const float* __restrict__ bias,
      float* __restrict__ out)
{
  int b = blockIdx.x;
  int tid = threadIdx.x;
  __shared__ float f[NQ];
  __shared__ float lg[128];
  __shared__ float red[128];
  if (tid < NQ) f[tid] = expv[b*NQ + tid];
  __syncthreads();
  float acc = -1e30f;
  if (tid < NCLS){
    acc = bias[tid];
    #pragma unroll
    for (int i=0;i<NQ;i++) acc += f[i]*W[tid*NQ+i];
  }
  lg[tid] = acc;
  red[tid] = acc;
  __syncthreads();
  #pragma unroll
  for (int sft=64; sft>0; sft>>=1){
    if (tid < sft) red[tid] = fmaxf(red[tid], red[tid+sft]);
    __syncthreads();
  }
  float m = red[0];
  __syncthreads();
  float e = (tid < NCLS) ? expf(lg[tid]-m) : 0.f;
  red[tid] = e;
  __syncthreads();
  #pragma unroll
  for (int sft=64; sft>0; sft>>=1){
    if (tid < sft) red[tid] = red[tid] + red[tid+sft];
    __syncthreads();
  }
  float lsum = logf(red[0]);
  if (tid < NCLS) out[b*NCLS+tid] = lg[tid] - m - lsum;
}

extern "C" void kernel_launch(void* const* d_in, const int* in_sizes, int n_in,
                              void* d_out, int out_size, void* d_ws, size_t ws_size,
                              hipStream_t stream)
{
  const float* x    = (const float*)d_in[0];
  const float* rot1 = (const float*)d_in[1];
  const float* crx1 = (const float*)d_in[2];
  const float* rot2 = (const float*)d_in[3];
  const float* crx2 = (const float*)d_in[4];
  const float* W    = (const float*)d_in[5];
  const float* bias = (const float*)d_in[6];
  float* out = (float*)d_out;

  char* ws = (char*)d_ws;
  float* expv = (float*)ws;                           // 32 KB  @ 0
  v2f*   fU   = (v2f*)(ws + (40<<10));                // 512 KB @ 40K
  v2f*   cmm  = (v2f*)(ws + (560<<10));               // 256 B  @ 560K
  v2f*   Tbl  = (v2f*)(ws + (564<<10));               // 128 KB @ 564K
  _Float16* Bt16  = (_Float16*)(ws + (704<<10));      // 4 MB   @ 704K   (pass3)
  _Float16* Bt16b = (_Float16*)(ws + (4800<<10));     // 4 MB   @ 4800K  (pass2)
  f16x2* compact = (f16x2*)(ws + (8896<<10));         // 8 MB   @ 8896K
  const size_t stOff = (size_t)(8896<<10) + ((size_t)NBATCH<<14);   // 17088K
  unsigned short* st = (unsigned short*)(ws + stOff); // 64 MB (fp8 pairs)

  kprep<<<(2*NBATCH*NQ + 255)/256, 256, 0, stream>>>(x, rot1, crx1, rot2, crx2, fU, cmm, expv);

  v2f* fU1 = fU;
  v2f* fU2 = fU + 32768;
  v2f* cm1 = cmm;
  v2f* cm2 = cmm + 16;

  kprepGall<<<(2*32768 + 2*NBATCH + 255)/256, 256, 0, stream>>>(fU1, fU2, cm1, cm2, Bt16, Bt16b, Tbl);
  kpass1<<<NBATCH, 256, 0, stream>>>(fU1, cm1, compact);

  size_t avail = (ws_size > stOff) ? (ws_size - stOff) : 0;
  int chunk = NBATCH;
  while (chunk > 1 && (size_t)chunk*65536*sizeof(unsigned short) > avail) chunk >>= 1;

  for (int b0 = 0; b0 < NBATCH; b0 += chunk){
    kpass2<<<chunk*16, 256, 0, stream>>>(compact, Tbl, (const half8*)Bt16b, st, b0);
    kpass3<<<chunk*16, 256, 0, stream>>>(st, fU2, cm2, (const half8*)Bt16, expv, b0);
  }
  klogits<<<NBATCH, 128, 0, stream>>>(expv, W, bias, out);
}